// Round 1
// baseline (869.529 us; speedup 1.0000x reference)
//
#include <hip/hip_runtime.h>
#include <math.h>

// ---- problem constants (match reference) ----
static constexpr int NYI  = 256;           // interior
static constexpr int PMLW = 20;            // pml width
static constexpr int NY   = NYI + 2*PMLW;  // 296
static constexpr int NX   = NYI + 2*PMLW;  // 296
static constexpr int NCELL = NY * NX;      // 87616
static constexpr int NS   = 2;             // shots
static constexpr int NSRC = 8;
static constexpr int NREC = 64;
static constexpr int NT   = 64;
static constexpr float DXF = 4.0f;
static constexpr float DTF = 5e-4f;
static constexpr float FC1 = 9.0f / 8.0f;
static constexpr float FC2 = -1.0f / 24.0f;
static constexpr float INV_DX = 1.0f / DXF;

// ---- field indices ----
enum { VY=0, VX, SYY, SXY, SXX, MVYY, MVYX, MVXY, MVXX, MSYYY, MSXYY, MSXYX, MSXXX, NFIELD };

// ---- workspace layout (floats) ----
static constexpr int MOFF    = NFIELD * NS * NCELL;   // materials: buoyp,l2m,lambp,mup (each NCELL)
static constexpr int BY_OFF  = MOFF + 4 * NCELL;
static constexpr int AY_OFF  = BY_OFF + 512;
static constexpr int BX_OFF  = BY_OFF + 1024;
static constexpr int AX_OFF  = BY_OFF + 1536;
static constexpr int SIG_OFF = BY_OFF + 2048;         // max_vel (reduction target)
static constexpr int SRCB_OFF= SIG_OFF + 16;          // buoyancy at sources [NS*NSRC]
static constexpr int WS_FLOATS = SRCB_OFF + 32;

__device__ __forceinline__ float ldz(const float* f, int y, int x) {
    return (y >= 0 && y < NY && x >= 0 && x < NX) ? f[y * NX + x] : 0.0f;
}

// Pad materials (edge replication == index clamp), and reduce max wave speed.
__global__ void prep_mats(const float* __restrict__ lamb, const float* __restrict__ mu,
                          const float* __restrict__ buoy, float* __restrict__ ws) {
    int i = blockIdx.x * blockDim.x + threadIdx.x;
    float v = 0.0f;
    if (i < NCELL) {
        int y = i / NX, x = i - (i / NX) * NX;
        int iy = min(max(y - PMLW, 0), NYI - 1);
        int ix = min(max(x - PMLW, 0), NYI - 1);
        float la = lamb[iy * NYI + ix];
        float m  = mu  [iy * NYI + ix];
        float b  = buoy[iy * NYI + ix];
        float l2m = la + 2.0f * m;
        ws[MOFF + 0 * NCELL + i] = b;
        ws[MOFF + 1 * NCELL + i] = l2m;
        ws[MOFF + 2 * NCELL + i] = la;
        ws[MOFF + 3 * NCELL + i] = m;
        v = sqrtf(l2m * b);
    }
    // wave-64 max reduction, then one atomic per wave (all values >= 0 -> int-bit compare ok)
    for (int off = 32; off > 0; off >>= 1)
        v = fmaxf(v, __shfl_down(v, off));
    if ((threadIdx.x & 63) == 0)
        atomicMax((int*)(ws + SIG_OFF), __float_as_int(v));
}

// CPML profiles + per-source buoyancy. Single block.
__global__ void prep_prof(const int* __restrict__ src_loc, float* __restrict__ ws) {
    float max_vel = ws[SIG_OFF];
    float sig_max = 3.0f * max_vel * logf(1000.0f) / (2.0f * PMLW * DXF);
    int i = threadIdx.x;
    if (i < NY) {  // NY == NX: one profile serves both axes
        float fi = (float)i;
        float d1 = fmaxf((float)PMLW - fi, 0.0f);
        float d2 = fmaxf(fi - (float)(NY - 1 - PMLW), 0.0f);
        float d  = fmaxf(d1, d2) * (1.0f / (float)PMLW);
        float b  = expf(-(sig_max * d * d) * DTF);
        ws[BY_OFF + i] = b;  ws[AY_OFF + i] = b - 1.0f;
        ws[BX_OFF + i] = b;  ws[AX_OFF + i] = b - 1.0f;
    }
    if (i < NS * NSRC) {
        int sy = src_loc[i * 2 + 0] + PMLW;
        int sx = src_loc[i * 2 + 1] + PMLW;
        ws[SRCB_OFF + i] = ws[MOFF + 0 * NCELL + sy * NX + sx];
    }
}

// Velocity half-step + CPML memory update + source injection into vy.
__global__ __launch_bounds__(256) void vel_step(float* __restrict__ ws,
                                                const float* __restrict__ amps,
                                                const int* __restrict__ src_loc, int t) {
    int gid = blockIdx.x * blockDim.x + threadIdx.x;
    if (gid >= NS * NCELL) return;
    int shot = gid / NCELL, cell = gid - shot * NCELL;
    int y = cell / NX, x = cell - y * NX;

    const float* syy = ws + (SYY * NS + shot) * NCELL;
    const float* sxy = ws + (SXY * NS + shot) * NCELL;
    const float* sxx = ws + (SXX * NS + shot) * NCELL;
    float* vy    = ws + (VY    * NS + shot) * NCELL;
    float* vx    = ws + (VX    * NS + shot) * NCELL;
    float* msyyy = ws + (MSYYY * NS + shot) * NCELL;
    float* msxyy = ws + (MSXYY * NS + shot) * NCELL;
    float* msxyx = ws + (MSXYX * NS + shot) * NCELL;
    float* msxxx = ws + (MSXXX * NS + shot) * NCELL;

    float by = ws[BY_OFF + y], ay = ws[AY_OFF + y];
    float bx = ws[BX_OFF + x], ax = ws[AX_OFF + x];
    float buo = ws[MOFF + 0 * NCELL + cell];

    // d/dy- of syy
    float d = (FC1 * (ldz(syy,y,x) - ldz(syy,y-1,x)) + FC2 * (ldz(syy,y+1,x) - ldz(syy,y-2,x))) * INV_DX;
    float m = by * msyyy[cell] + ay * d;  msyyy[cell] = m;  float dsyy_y = d + m;
    // d/dx- of sxy
    d = (FC1 * (ldz(sxy,y,x) - ldz(sxy,y,x-1)) + FC2 * (ldz(sxy,y,x+1) - ldz(sxy,y,x-2))) * INV_DX;
    m = bx * msxyx[cell] + ax * d;  msxyx[cell] = m;  float dsxy_x = d + m;
    float vy_new = vy[cell] + DTF * buo * (dsyy_y + dsxy_x);
    // d/dy- of sxy
    d = (FC1 * (ldz(sxy,y,x) - ldz(sxy,y-1,x)) + FC2 * (ldz(sxy,y+1,x) - ldz(sxy,y-2,x))) * INV_DX;
    m = by * msxyy[cell] + ay * d;  msxyy[cell] = m;  float dsxy_y = d + m;
    // d/dx- of sxx
    d = (FC1 * (ldz(sxx,y,x) - ldz(sxx,y,x-1)) + FC2 * (ldz(sxx,y,x+1) - ldz(sxx,y,x-2))) * INV_DX;
    m = bx * msxxx[cell] + ax * d;  msxxx[cell] = m;  float dsxx_x = d + m;
    float vx_new = vx[cell] + DTF * buo * (dsxy_y + dsxx_x);

    // source injection (duplicate locations accumulate, matching .at[].add)
    #pragma unroll
    for (int s = 0; s < NSRC; ++s) {
        int sy = src_loc[(shot * NSRC + s) * 2 + 0] + PMLW;
        int sx = src_loc[(shot * NSRC + s) * 2 + 1] + PMLW;
        if (sy == y && sx == x)
            vy_new += DTF * ws[SRCB_OFF + shot * NSRC + s] * amps[(shot * NSRC + s) * NT + t];
    }
    vy[cell] = vy_new;
    vx[cell] = vx_new;
}

// Stress half-step + CPML memory update; also records receivers (vy is not modified here).
__global__ __launch_bounds__(256) void str_step(float* __restrict__ ws,
                                                const int* __restrict__ rec_loc,
                                                float* __restrict__ out, int t) {
    int gid = blockIdx.x * blockDim.x + threadIdx.x;
    if (gid < NS * NREC) {
        int shot = gid / NREC, r = gid - shot * NREC;
        int ry = rec_loc[(shot * NREC + r) * 2 + 0] + PMLW;
        int rx = rec_loc[(shot * NREC + r) * 2 + 1] + PMLW;
        out[(shot * NREC + r) * NT + t] = ws[(VY * NS + shot) * NCELL + ry * NX + rx];
    }
    if (gid >= NS * NCELL) return;
    int shot = gid / NCELL, cell = gid - shot * NCELL;
    int y = cell / NX, x = cell - y * NX;

    const float* vy = ws + (VY * NS + shot) * NCELL;
    const float* vx = ws + (VX * NS + shot) * NCELL;
    float* syy  = ws + (SYY  * NS + shot) * NCELL;
    float* sxy  = ws + (SXY  * NS + shot) * NCELL;
    float* sxx  = ws + (SXX  * NS + shot) * NCELL;
    float* mvyy = ws + (MVYY * NS + shot) * NCELL;
    float* mvyx = ws + (MVYX * NS + shot) * NCELL;
    float* mvxy = ws + (MVXY * NS + shot) * NCELL;
    float* mvxx = ws + (MVXX * NS + shot) * NCELL;

    float by = ws[BY_OFF + y], ay = ws[AY_OFF + y];
    float bx = ws[BX_OFF + x], ax = ws[AX_OFF + x];
    float l2m = ws[MOFF + 1 * NCELL + cell];
    float lam = ws[MOFF + 2 * NCELL + cell];
    float muv = ws[MOFF + 3 * NCELL + cell];

    // d/dy+ of vy
    float d = (FC1 * (ldz(vy,y+1,x) - ldz(vy,y,x)) + FC2 * (ldz(vy,y+2,x) - ldz(vy,y-1,x))) * INV_DX;
    float m = by * mvyy[cell] + ay * d;  mvyy[cell] = m;  float dvy_y = d + m;
    // d/dx+ of vx
    d = (FC1 * (ldz(vx,y,x+1) - ldz(vx,y,x)) + FC2 * (ldz(vx,y,x+2) - ldz(vx,y,x-1))) * INV_DX;
    m = bx * mvxx[cell] + ax * d;  mvxx[cell] = m;  float dvx_x = d + m;
    syy[cell] += DTF * (l2m * dvy_y + lam * dvx_x);
    sxx[cell] += DTF * (lam * dvy_y + l2m * dvx_x);
    // d/dx+ of vy
    d = (FC1 * (ldz(vy,y,x+1) - ldz(vy,y,x)) + FC2 * (ldz(vy,y,x+2) - ldz(vy,y,x-1))) * INV_DX;
    m = bx * mvyx[cell] + ax * d;  mvyx[cell] = m;  float dvy_x = d + m;
    // d/dy+ of vx
    d = (FC1 * (ldz(vx,y+1,x) - ldz(vx,y,x)) + FC2 * (ldz(vx,y+2,x) - ldz(vx,y-1,x))) * INV_DX;
    m = by * mvxy[cell] + ay * d;  mvxy[cell] = m;  float dvx_y = d + m;
    sxy[cell] += DTF * muv * (dvy_x + dvx_y);
}

extern "C" void kernel_launch(void* const* d_in, const int* in_sizes, int n_in,
                              void* d_out, int out_size, void* d_ws, size_t ws_size,
                              hipStream_t stream) {
    const float* lamb    = (const float*)d_in[0];
    const float* mu      = (const float*)d_in[1];
    const float* buoy    = (const float*)d_in[2];
    const float* amps    = (const float*)d_in[3];
    const int*   src_loc = (const int*)d_in[4];
    const int*   rec_loc = (const int*)d_in[5];
    float* ws  = (float*)d_ws;
    float* out = (float*)d_out;

    // zero state + reduction scalar (ws is poisoned 0xAA before every call)
    hipMemsetAsync(d_ws, 0, (size_t)WS_FLOATS * sizeof(float), stream);

    prep_mats<<<(NCELL + 255) / 256, 256, 0, stream>>>(lamb, mu, buoy, ws);
    prep_prof<<<1, 512, 0, stream>>>(src_loc, ws);

    int blocks = (NS * NCELL + 255) / 256;
    for (int t = 0; t < NT; ++t) {
        vel_step<<<blocks, 256, 0, stream>>>(ws, amps, src_loc, t);
        str_step<<<blocks, 256, 0, stream>>>(ws, rec_loc, out, t);
    }
}